// Round 1
// baseline (108.587 us; speedup 1.0000x reference)
//
#include <hip/hip_runtime.h>

// WaveletTransformLayer: Haar DWT along sequence axis.
// x: (B=16, S=8192, C=512) fp32. out: (B, S, C) with
//   out[b, s, c]        = (x[b,2s,c] + x[b,2s+1,c]) * INV_SQRT2   (s < S/2)
//   out[b, S/2 + s, c]  = (x[b,2s,c] - x[b,2s+1,c]) * INV_SQRT2
//
// Memory-bound: 256 MiB in + 256 MiB out. Strategy: float4 vectorized
// grid-stride loop, one thread = 4 channels of one (b, s) pair.

#define B_DIM 16
#define S_DIM 8192
#define C_DIM 512
#define C4 (C_DIM / 4)            // 128 float4 per row
#define SHALF (S_DIM / 2)         // 4096
#define TOTAL4 ((long)B_DIM * SHALF * C4)  // 8,388,608 float4-pairs

__global__ __launch_bounds__(256) void wavelet_haar_kernel(
    const float4* __restrict__ x, float4* __restrict__ out) {
    const float inv_sqrt2 = 0.70710678118654752440f;
    long stride = (long)gridDim.x * blockDim.x;
    for (long i = (long)blockIdx.x * blockDim.x + threadIdx.x; i < TOTAL4; i += stride) {
        // decompose i -> (b, s, c4).  C4=128 (2^7), SHALF=4096 (2^12)
        long c4 = i & (C4 - 1);
        long rest = i >> 7;            // b*SHALF + s
        long s = rest & (SHALF - 1);
        long b = rest >> 12;

        long in_even = (((b * S_DIM) + 2 * s) << 7) + c4;   // float4 index
        float4 e = x[in_even];
        float4 o = x[in_even + C4];

        float4 a, d;
        a.x = (e.x + o.x) * inv_sqrt2;
        a.y = (e.y + o.y) * inv_sqrt2;
        a.z = (e.z + o.z) * inv_sqrt2;
        a.w = (e.w + o.w) * inv_sqrt2;
        d.x = (e.x - o.x) * inv_sqrt2;
        d.y = (e.y - o.y) * inv_sqrt2;
        d.z = (e.z - o.z) * inv_sqrt2;
        d.w = (e.w - o.w) * inv_sqrt2;

        long outA = (((b * S_DIM) + s) << 7) + c4;
        long outD = (((b * S_DIM) + SHALF + s) << 7) + c4;
        out[outA] = a;
        out[outD] = d;
    }
}

extern "C" void kernel_launch(void* const* d_in, const int* in_sizes, int n_in,
                              void* d_out, int out_size, void* d_ws, size_t ws_size,
                              hipStream_t stream) {
    const float4* x = (const float4*)d_in[0];
    float4* out = (float4*)d_out;
    // Grid: cap at 2048 blocks (256 CU * 8 blocks/CU), grid-stride the rest.
    int threads = 256;
    long total_threads_needed = TOTAL4;  // one float4-pair per thread-iter
    int blocks = (int)((total_threads_needed + threads - 1) / threads);
    if (blocks > 2048) blocks = 2048;
    wavelet_haar_kernel<<<blocks, threads, 0, stream>>>(x, out);
}

// Round 2
// 98.158 us; speedup vs baseline: 1.1062x; 1.1062x over previous
//
#include <hip/hip_runtime.h>

// WaveletTransformLayer: Haar DWT along sequence axis.
// x: (B=16, S=8192, C=512) fp32. out[b,s,c] = (x[b,2s,c]+x[b,2s+1,c])/sqrt2 ;
// out[b,S/2+s,c] = (x[b,2s,c]-x[b,2s+1,c])/sqrt2.
//
// Memory-bound (256 MiB in + 256 MiB out, streaming, zero reuse).
// R2 strategy: max MLP — each thread owns 4 pairs at a CONSTANT address
// stride (grid covers exactly 4 b-slices per "pass", so the 4 items share
// s,c4 and differ only by b += 4). 8 independent nontemporal float4 loads
// issued back-to-back, then compute + 8 nontemporal stores. No loop, no
// bounds checks: 16*4096*128 = 8,388,608 pairs = 8192 blocks * 256 thr * 4.

typedef float f32x4 __attribute__((ext_vector_type(4)));

#define B_DIM 16
#define S_DIM 8192
#define C_DIM 512
#define C4 (C_DIM / 4)        // 128 float4 per row
#define SHALF (S_DIM / 2)     // 4096
#define UNROLL 4
#define NTHREADS 256
#define NBLOCKS 8192          // NBLOCKS*NTHREADS*UNROLL == B*SHALF*C4 exactly

__global__ __launch_bounds__(NTHREADS) void wavelet_haar_kernel(
    const f32x4* __restrict__ x, f32x4* __restrict__ out) {
    const float r = 0.70710678118654752440f;

    // base in [0, 2^21): covers b-slices 0..3; item k adds 4 to b.
    unsigned base = blockIdx.x * NTHREADS + threadIdx.x;
    unsigned c4 = base & (C4 - 1);
    unsigned s  = (base >> 7) & (SHALF - 1);
    unsigned b0 = base >> 19;                        // 0..3

    const long ITEM = 4L * S_DIM * C4;               // float4 stride: b += 4
    long inE = ((long)b0 * S_DIM + 2 * s) * C4 + c4; // even row, item 0
    long oA  = ((long)b0 * S_DIM + s) * C4 + c4;     // cA row, item 0
    long oD  = oA + (long)SHALF * C4;                // cD row, item 0

    f32x4 e[UNROLL], o[UNROLL];
#pragma unroll
    for (int k = 0; k < UNROLL; ++k) {
        e[k] = __builtin_nontemporal_load(x + inE + k * ITEM);
        o[k] = __builtin_nontemporal_load(x + inE + k * ITEM + C4);
    }
#pragma unroll
    for (int k = 0; k < UNROLL; ++k) {
        f32x4 a = (e[k] + o[k]) * r;
        f32x4 d = (e[k] - o[k]) * r;
        __builtin_nontemporal_store(a, out + oA + k * ITEM);
        __builtin_nontemporal_store(d, out + oD + k * ITEM);
    }
}

extern "C" void kernel_launch(void* const* d_in, const int* in_sizes, int n_in,
                              void* d_out, int out_size, void* d_ws, size_t ws_size,
                              hipStream_t stream) {
    const f32x4* x = (const f32x4*)d_in[0];
    f32x4* out = (f32x4*)d_out;
    wavelet_haar_kernel<<<NBLOCKS, NTHREADS, 0, stream>>>(x, out);
}

// Round 3
// 91.756 us; speedup vs baseline: 1.1834x; 1.0698x over previous
//
#include <hip/hip_runtime.h>

// WaveletTransformLayer: Haar DWT along sequence axis.
// x: (B=16, S=8192, C=512) fp32. out[b,s,c] = (x[b,2s,c]+x[b,2s+1,c])/sqrt2 ;
// out[b,S/2+s,c] = (x[b,2s,c]-x[b,2s+1,c])/sqrt2.
//
// Memory-bound (256 MiB in + 256 MiB out, streaming, zero reuse).
// R3: contiguous-block layout + deeper MLP. Flatten i over (b,s,c4); each
// block owns 2048 consecutive i (= 16 consecutive s rows of one b, full c4),
// each thread owns 8 items at constant stride +256 i (= s += 2). One address
// decomposition, 16 independent nontemporal float4 loads back-to-back, then
// compute + 16 nontemporal stores. Per block: one 32 KB contiguous read run,
// two 16 KB contiguous write runs (copy-like DRAM locality).
// 16*4096*128 = 8,388,608 items = 4096 blocks * 256 thr * 8 exactly.

typedef float f32x4 __attribute__((ext_vector_type(4)));

#define B_DIM 16
#define S_DIM 8192
#define C_DIM 512
#define C4 (C_DIM / 4)        // 128 float4 per row
#define SHALF (S_DIM / 2)     // 4096
#define UNROLL 8
#define NTHREADS 256
#define NBLOCKS 4096
#define BLOCK_ITEMS (NTHREADS * UNROLL)   // 2048

__global__ __launch_bounds__(NTHREADS) void wavelet_haar_kernel(
    const f32x4* __restrict__ x, f32x4* __restrict__ out) {
    const float r = 0.70710678118654752440f;

    // i in [0, 2^23): flattened (b, s, c4). Items: i += k*256 -> s += 2k.
    unsigned base = blockIdx.x * BLOCK_ITEMS + threadIdx.x;
    unsigned c4 = base & (C4 - 1);
    unsigned s  = (base >> 7) & (SHALF - 1);
    unsigned b  = base >> 19;

    long inE = ((long)b * S_DIM + 2 * s) * C4 + c4;  // even row, item 0
    long oA  = ((long)b * S_DIM + s) * C4 + c4;      // cA row, item 0
    long oD  = oA + (long)SHALF * C4;                // cD row, item 0
    const long IN_STRIDE  = 4L * C4;   // s += 2 -> even-row float4 idx += 512
    const long OUT_STRIDE = 2L * C4;   // s += 2 -> out float4 idx += 256

    f32x4 e[UNROLL], o[UNROLL];
#pragma unroll
    for (int k = 0; k < UNROLL; ++k) {
        e[k] = __builtin_nontemporal_load(x + inE + k * IN_STRIDE);
        o[k] = __builtin_nontemporal_load(x + inE + k * IN_STRIDE + C4);
    }
#pragma unroll
    for (int k = 0; k < UNROLL; ++k) {
        f32x4 a = (e[k] + o[k]) * r;
        f32x4 d = (e[k] - o[k]) * r;
        __builtin_nontemporal_store(a, out + oA + k * OUT_STRIDE);
        __builtin_nontemporal_store(d, out + oD + k * OUT_STRIDE);
    }
}

extern "C" void kernel_launch(void* const* d_in, const int* in_sizes, int n_in,
                              void* d_out, int out_size, void* d_ws, size_t ws_size,
                              hipStream_t stream) {
    const f32x4* x = (const f32x4*)d_in[0];
    f32x4* out = (f32x4*)d_out;
    wavelet_haar_kernel<<<NBLOCKS, NTHREADS, 0, stream>>>(x, out);
}